// Round 6
// baseline (2463.922 us; speedup 1.0000x reference)
//
#include <hip/hip_runtime.h>

#define HDIM 256
#define EPSV 1e-5f
#define SLOPEV 0.01f

typedef __bf16 bf16;
typedef bf16  bf16x8 __attribute__((ext_vector_type(8)));
typedef bf16  bf16x4 __attribute__((ext_vector_type(4)));
typedef float f32x4  __attribute__((ext_vector_type(4)));

#define GLD16(g, l) __builtin_amdgcn_global_load_lds( \
    (const __attribute__((address_space(1))) void*)(g), \
    (__attribute__((address_space(3))) void*)(l), 16, 0, 0)

// ================= MFMA GEMM with fused BN-apply (A-side) and BN-stats (epilogue) ===
// out = concat_k(A0..A_{nseg-1}) * Wt^T + bias (+addb residual).
// xmask bit s: apply leaky(a*x+b) to A seg s while staging (coeffs from raw stats).
// ostats: accumulate column sum/sumsq of stored values (rows < n_stats).
template<bool STORE_BF16>
__global__ __launch_bounds__(256)
void gemm_bt_k(const bf16* A0, const bf16* A1, const bf16* A2, const bf16* A3,
               int nseg, int segK, unsigned xmask,
               const float* xstats, const float* xg, const float* xbb, int Kx,
               const bf16* __restrict__ Wt,
               const float* __restrict__ bias, const bf16* __restrict__ addb,
               void* out0, void* out1, void* out2, void* out3, int ldo,
               int n_store, float* ostats, int Kostat, int n_stats, float invn)
{
    __shared__ char smem[24576];
    bf16* As = (bf16*)smem;              // [128][32] bf16, 8 KB
    bf16* Bs = (bf16*)(smem + 8192);     // [128][32] bf16, 8 KB
    float* afL = (float*)(smem + 16384); // Kx <= 1024
    float* bfL = (float*)(smem + 20480);

    const int tid = threadIdx.x;
    const int wave = tid >> 6, lane = tid & 63;
    const int quad = lane >> 4, l16 = lane & 15;
    const int waveM = (wave >> 1) * 64, waveN = (wave & 1) * 64;
    const int bm = blockIdx.y * 128, bn = blockIdx.x * 128;
    const int K = nseg * segK;

    if (xmask) {
        for (int c = tid; c < Kx; c += 256) {
            float mean = xstats[c] * invn;
            float var  = xstats[Kx + c] * invn - mean * mean;
            float a = xg[c] * rsqrtf(var + EPSV);
            afL[c] = a; bfL[c] = xbb[c] - mean * a;
        }
    }
    __syncthreads();

    const bf16* segs[4] = {A0, A1, A2, A3};
    char* lA0 = (char*)As + wave * 1024;
    char* lA1 = (char*)As + 4096 + wave * 1024;
    char* lB0 = (char*)Bs + wave * 1024;
    char* lB1 = (char*)Bs + 4096 + wave * 1024;
    const bf16* pa = As + (waveM + l16) * 32 + quad * 8;
    const bf16* pb = Bs + (waveN + l16) * 32 + quad * 8;

    f32x4 acc[4][4] = {};

    for (int s = 0; s < nseg; ++s) {
        const bf16* A = segs[s];
        const bool xf = (xmask >> s) & 1;
        const bf16* gA0 = A + (size_t)(bm + (tid >> 2)) * segK + (tid & 3) * 8;
        const bf16* gA1 = A + (size_t)(bm + 64 + (tid >> 2)) * segK + (tid & 3) * 8;
        const bf16* gB0 = Wt + (size_t)(bn + (tid >> 2)) * K + s * segK + (tid & 3) * 8;
        const bf16* gB1 = Wt + (size_t)(bn + 64 + (tid >> 2)) * K + s * segK + (tid & 3) * 8;
        for (int kt = 0; kt < segK; kt += 32) {
            if (xf) {
                int kb = s * segK + kt + (tid & 3) * 8;
                bf16x8 v0 = *(const bf16x8*)gA0;
                bf16x8 v1 = *(const bf16x8*)gA1;
                const float* af8 = &afL[kb];
                const float* bf8 = &bfL[kb];
                bf16x8 w0, w1;
#pragma unroll
                for (int u = 0; u < 8; ++u) {
                    float f0 = fmaf((float)v0[u], af8[u], bf8[u]);
                    w0[u] = (bf16)(f0 > 0.f ? f0 : SLOPEV * f0);
                    float f1 = fmaf((float)v1[u], af8[u], bf8[u]);
                    w1[u] = (bf16)(f1 > 0.f ? f1 : SLOPEV * f1);
                }
                *(bf16x8*)((char*)As + tid * 16) = w0;
                *(bf16x8*)((char*)As + 4096 + tid * 16) = w1;
            } else {
                GLD16(gA0, lA0); GLD16(gA1, lA1);
            }
            GLD16(gB0, lB0); GLD16(gB1, lB1);
            gA0 += 32; gA1 += 32; gB0 += 32; gB1 += 32;
            __syncthreads();

            bf16x8 a0 = *(const bf16x8*)(pa);
            bf16x8 a1 = *(const bf16x8*)(pa + 16 * 32);
            bf16x8 a2 = *(const bf16x8*)(pa + 32 * 32);
            bf16x8 a3 = *(const bf16x8*)(pa + 48 * 32);
            bf16x8 b0 = *(const bf16x8*)(pb);
            bf16x8 b1 = *(const bf16x8*)(pb + 16 * 32);
            bf16x8 b2 = *(const bf16x8*)(pb + 32 * 32);
            bf16x8 b3 = *(const bf16x8*)(pb + 48 * 32);

            acc[0][0] = __builtin_amdgcn_mfma_f32_16x16x32_bf16(a0, b0, acc[0][0], 0, 0, 0);
            acc[0][1] = __builtin_amdgcn_mfma_f32_16x16x32_bf16(a0, b1, acc[0][1], 0, 0, 0);
            acc[0][2] = __builtin_amdgcn_mfma_f32_16x16x32_bf16(a0, b2, acc[0][2], 0, 0, 0);
            acc[0][3] = __builtin_amdgcn_mfma_f32_16x16x32_bf16(a0, b3, acc[0][3], 0, 0, 0);
            acc[1][0] = __builtin_amdgcn_mfma_f32_16x16x32_bf16(a1, b0, acc[1][0], 0, 0, 0);
            acc[1][1] = __builtin_amdgcn_mfma_f32_16x16x32_bf16(a1, b1, acc[1][1], 0, 0, 0);
            acc[1][2] = __builtin_amdgcn_mfma_f32_16x16x32_bf16(a1, b2, acc[1][2], 0, 0, 0);
            acc[1][3] = __builtin_amdgcn_mfma_f32_16x16x32_bf16(a1, b3, acc[1][3], 0, 0, 0);
            acc[2][0] = __builtin_amdgcn_mfma_f32_16x16x32_bf16(a2, b0, acc[2][0], 0, 0, 0);
            acc[2][1] = __builtin_amdgcn_mfma_f32_16x16x32_bf16(a2, b1, acc[2][1], 0, 0, 0);
            acc[2][2] = __builtin_amdgcn_mfma_f32_16x16x32_bf16(a2, b2, acc[2][2], 0, 0, 0);
            acc[2][3] = __builtin_amdgcn_mfma_f32_16x16x32_bf16(a2, b3, acc[2][3], 0, 0, 0);
            acc[3][0] = __builtin_amdgcn_mfma_f32_16x16x32_bf16(a3, b0, acc[3][0], 0, 0, 0);
            acc[3][1] = __builtin_amdgcn_mfma_f32_16x16x32_bf16(a3, b1, acc[3][1], 0, 0, 0);
            acc[3][2] = __builtin_amdgcn_mfma_f32_16x16x32_bf16(a3, b2, acc[3][2], 0, 0, 0);
            acc[3][3] = __builtin_amdgcn_mfma_f32_16x16x32_bf16(a3, b3, acc[3][3], 0, 0, 0);
            __syncthreads();
        }
    }

    // bias into acc
    float bv[4];
#pragma unroll
    for (int j = 0; j < 4; ++j)
        bv[j] = bias ? bias[bn + waveN + j * 16 + l16] : 0.f;
#pragma unroll
    for (int i = 0; i < 4; ++i)
#pragma unroll
        for (int j = 0; j < 4; ++j)
#pragma unroll
            for (int r = 0; r < 4; ++r)
                acc[i][j][r] += bv[j];

    void* outs[4] = {out0, out1, out2, out3};

    if (STORE_BF16) {
        // stage per-wave 32x64 tile (row stride 68 bf16: conflict-free b16 writes)
        char* stg = smem + wave * 4352;
        float s8[8] = {}, q8[8] = {};
        const int rsel = lane >> 3, csel = lane & 7;
#pragma unroll
        for (int ih = 0; ih < 2; ++ih) {
            __syncthreads();
#pragma unroll
            for (int iw = 0; iw < 2; ++iw) {
                int i = ih * 2 + iw;
#pragma unroll
                for (int j = 0; j < 4; ++j)
#pragma unroll
                    for (int r = 0; r < 4; ++r)
                        *(bf16*)(stg + ((iw * 16 + quad * 4 + r) * 68 + j * 16 + l16) * 2)
                            = (bf16)acc[i][j][r];
            }
            __syncthreads();
#pragma unroll
            for (int rr = 0; rr < 4; ++rr) {
                int rl = rsel + rr * 8;
                bf16x4 lo = *(const bf16x4*)(stg + (rl * 68 + csel * 8) * 2);
                bf16x4 hi = *(const bf16x4*)(stg + (rl * 68 + csel * 8 + 4) * 2);
                int rowg = bm + waveM + ih * 32 + rl;
                int colg = bn + waveN + csel * 8;
                int cseg = colg >> 8, cloc = colg & 255;
                size_t idx = (size_t)rowg * ldo + cloc;
                float f[8];
#pragma unroll
                for (int u = 0; u < 4; ++u) { f[u] = (float)lo[u]; f[4 + u] = (float)hi[u]; }
                if (addb) {
                    bf16x8 o = *(const bf16x8*)(addb + idx);
#pragma unroll
                    for (int u = 0; u < 8; ++u) f[u] += (float)o[u];
                }
                bf16x8 w;
#pragma unroll
                for (int u = 0; u < 8; ++u) w[u] = (bf16)f[u];
                if (rowg < n_store) *(bf16x8*)((bf16*)outs[cseg] + idx) = w;
                if (ostats && rowg < n_stats) {
#pragma unroll
                    for (int u = 0; u < 8; ++u) { s8[u] += f[u]; q8[u] += f[u] * f[u]; }
                }
            }
        }
        if (ostats) {
#pragma unroll
            for (int m = 8; m <= 32; m <<= 1)
#pragma unroll
                for (int u = 0; u < 8; ++u) {
                    s8[u] += __shfl_xor(s8[u], m, 64);
                    q8[u] += __shfl_xor(q8[u], m, 64);
                }
            if (rsel == 0) {
                int colg = bn + waveN + csel * 8;
#pragma unroll
                for (int u = 0; u < 8; ++u) {
                    unsafeAtomicAdd(&ostats[colg + u], s8[u]);
                    unsafeAtomicAdd(&ostats[Kostat + colg + u], q8[u]);
                }
            }
        }
    } else {
        // f32 direct store (final projection only)
#pragma unroll
        for (int i = 0; i < 4; ++i)
#pragma unroll
            for (int j = 0; j < 4; ++j) {
                int colg = bn + waveN + j * 16 + l16;
                int cseg = colg >> 8, cloc = colg & 255;
#pragma unroll
                for (int r = 0; r < 4; ++r) {
                    int rowg = bm + waveM + i * 16 + quad * 4 + r;
                    if (rowg < n_store)
                        ((float*)outs[cseg])[(size_t)rowg * ldo + cloc] = acc[i][j][r];
                }
            }
    }
}

// ================= transpose+convert =================
__global__ __launch_bounds__(256)
void transpose_cvt_k(const float* __restrict__ src, bf16* __restrict__ dst,
                     int Kseg, int M, int G)
{
    __shared__ float t[32][33];
    const int z = blockIdx.z;
    src += (size_t)z * Kseg * M;
    const int ldd = G * Kseg;
    dst += (size_t)(z / G) * M * ldd + (size_t)(z % G) * Kseg;
    const int tM = blockIdx.x * 32, tK = blockIdx.y * 32;
    const int tx = threadIdx.x & 31, ty = threadIdx.x >> 5;
#pragma unroll
    for (int r = 0; r < 4; ++r)
        t[ty + r * 8][tx] = src[(size_t)(tK + ty + r * 8) * M + tM + tx];
    __syncthreads();
#pragma unroll
    for (int r = 0; r < 4; ++r)
        dst[(size_t)(tM + ty + r * 8) * ldd + tK + tx] = (bf16)t[tx][ty + r * 8];
}

__global__ __launch_bounds__(256)
void cvt_bf_k(const float* __restrict__ src, bf16* __restrict__ dst, long n4)
{
    long i = (long)blockIdx.x * blockDim.x + threadIdx.x;
    if (i >= n4) return;
    float4 v = ((const float4*)src)[i];
    bf16x4 o; o[0] = (bf16)v.x; o[1] = (bf16)v.y; o[2] = (bf16)v.z; o[3] = (bf16)v.w;
    ((bf16x4*)dst)[i] = o;
}

// ================= CSR build =================
__global__ __launch_bounds__(256)
void deg_k(const int* __restrict__ dst, int* __restrict__ deg, int E)
{
    int e = blockIdx.x * blockDim.x + threadIdx.x;
    if (e < E) atomicAdd(&deg[dst[e]], 1);
}

__global__ __launch_bounds__(1024)
void scan_k(int* __restrict__ deg_wp, int* __restrict__ rowptr, int N)
{
    __shared__ int s[1024];
    const int tid = threadIdx.x;
    if (tid == 0) rowptr[0] = 0;
    int running = 0;
    for (int base = 0; base < N; base += 1024) {
        int i = base + tid;
        int x = (i < N) ? deg_wp[i] : 0;
        s[tid] = x;
        __syncthreads();
        for (int off = 1; off < 1024; off <<= 1) {
            int t = (tid >= off) ? s[tid - off] : 0;
            __syncthreads();
            s[tid] += t;
            __syncthreads();
        }
        if (i < N) {
            rowptr[i + 1] = s[tid] + running;
            deg_wp[i]     = s[tid] + running - x;
        }
        running += s[1023];
        __syncthreads();
    }
}

__global__ __launch_bounds__(256)
void reorder_k(const int* __restrict__ src, const int* __restrict__ dst,
               const float* __restrict__ ew, int* __restrict__ wp,
               int* __restrict__ col, float* __restrict__ wgt, int E)
{
    int e = blockIdx.x * blockDim.x + threadIdx.x;
    if (e >= E) return;
    int d = dst[e];
    int pos = atomicAdd(&wp[d], 1);
    col[pos] = src[e];
    wgt[pos] = ew[e];
}

// ================= pull SpMM, optional fused BN+leaky on gather =================
__global__ __launch_bounds__(256)
void spmm_pull_k(const bf16* __restrict__ P, const int* __restrict__ rowptr,
                 const int* __restrict__ col, const float* __restrict__ wgt,
                 bf16* __restrict__ Q, int N,
                 const float* xstats, const float* xg, const float* xbb, float invn)
{
    __shared__ float aL[256], bL[256];
    const bool xf = (xstats != nullptr);
    if (xf) {
        int c = threadIdx.x;
        float mean = xstats[c] * invn;
        float var  = xstats[256 + c] * invn - mean * mean;
        float a = xg[c] * rsqrtf(var + EPSV);
        aL[c] = a; bL[c] = xbb[c] - mean * a;
    }
    __syncthreads();
    int node = blockIdx.x * 4 + (threadIdx.x >> 6);
    int lane = threadIdx.x & 63;
    if (node >= N) return;
    int e = rowptr[node], end = rowptr[node + 1];
    float ax = 0.f, ay = 0.f, az = 0.f, aw = 0.f;
    if (xf) {
        float a0 = aL[lane * 4 + 0], a1 = aL[lane * 4 + 1];
        float a2 = aL[lane * 4 + 2], a3 = aL[lane * 4 + 3];
        float b0 = bL[lane * 4 + 0], b1 = bL[lane * 4 + 1];
        float b2 = bL[lane * 4 + 2], b3 = bL[lane * 4 + 3];
        for (; e + 1 < end; e += 2) {
            int   s0 = col[e], s1 = col[e + 1];
            float w0 = wgt[e], w1 = wgt[e + 1];
            bf16x4 v0 = *(const bf16x4*)(P + (size_t)s0 * HDIM + lane * 4);
            bf16x4 v1 = *(const bf16x4*)(P + (size_t)s1 * HDIM + lane * 4);
            float t;
            t = fmaf((float)v0[0], a0, b0); t = t > 0.f ? t : SLOPEV * t; ax += w0 * t;
            t = fmaf((float)v0[1], a1, b1); t = t > 0.f ? t : SLOPEV * t; ay += w0 * t;
            t = fmaf((float)v0[2], a2, b2); t = t > 0.f ? t : SLOPEV * t; az += w0 * t;
            t = fmaf((float)v0[3], a3, b3); t = t > 0.f ? t : SLOPEV * t; aw += w0 * t;
            t = fmaf((float)v1[0], a0, b0); t = t > 0.f ? t : SLOPEV * t; ax += w1 * t;
            t = fmaf((float)v1[1], a1, b1); t = t > 0.f ? t : SLOPEV * t; ay += w1 * t;
            t = fmaf((float)v1[2], a2, b2); t = t > 0.f ? t : SLOPEV * t; az += w1 * t;
            t = fmaf((float)v1[3], a3, b3); t = t > 0.f ? t : SLOPEV * t; aw += w1 * t;
        }
        if (e < end) {
            int s0 = col[e]; float w0 = wgt[e];
            bf16x4 v0 = *(const bf16x4*)(P + (size_t)s0 * HDIM + lane * 4);
            float t;
            t = fmaf((float)v0[0], a0, b0); t = t > 0.f ? t : SLOPEV * t; ax += w0 * t;
            t = fmaf((float)v0[1], a1, b1); t = t > 0.f ? t : SLOPEV * t; ay += w0 * t;
            t = fmaf((float)v0[2], a2, b2); t = t > 0.f ? t : SLOPEV * t; az += w0 * t;
            t = fmaf((float)v0[3], a3, b3); t = t > 0.f ? t : SLOPEV * t; aw += w0 * t;
        }
    } else {
        for (; e + 1 < end; e += 2) {
            int   s0 = col[e], s1 = col[e + 1];
            float w0 = wgt[e], w1 = wgt[e + 1];
            bf16x4 v0 = *(const bf16x4*)(P + (size_t)s0 * HDIM + lane * 4);
            bf16x4 v1 = *(const bf16x4*)(P + (size_t)s1 * HDIM + lane * 4);
            ax += (float)v0[0] * w0 + (float)v1[0] * w1;
            ay += (float)v0[1] * w0 + (float)v1[1] * w1;
            az += (float)v0[2] * w0 + (float)v1[2] * w1;
            aw += (float)v0[3] * w0 + (float)v1[3] * w1;
        }
        if (e < end) {
            int s0 = col[e]; float w0 = wgt[e];
            bf16x4 v0 = *(const bf16x4*)(P + (size_t)s0 * HDIM + lane * 4);
            ax += (float)v0[0] * w0; ay += (float)v0[1] * w0;
            az += (float)v0[2] * w0; aw += (float)v0[3] * w0;
        }
    }
    bf16x4 o; o[0] = (bf16)ax; o[1] = (bf16)ay; o[2] = (bf16)az; o[3] = (bf16)aw;
    *(bf16x4*)(Q + (size_t)node * HDIM + lane * 4) = o;
}

// ================= host =================
struct GemmArgs {
    const bf16 *A0, *A1, *A2, *A3; int nseg, segK; unsigned xmask;
    const float *xstats, *xg, *xbb; int Kx;
    const bf16* Wt; const float* bias; const bf16* addb;
    void *o0, *o1, *o2, *o3; int ldo, M, n_store;
    float* ostats; int Kostat, n_stats;
};

static void gemm(hipStream_t st, const GemmArgs& a, int GY, float invn, bool store_bf16)
{
    dim3 g(a.M / 128, GY), b(256);
    if (store_bf16)
        gemm_bt_k<true><<<g, b, 0, st>>>(a.A0, a.A1, a.A2, a.A3, a.nseg, a.segK, a.xmask,
            a.xstats, a.xg, a.xbb, a.Kx, a.Wt, a.bias, a.addb,
            a.o0, a.o1, a.o2, a.o3, a.ldo, a.n_store, a.ostats, a.Kostat, a.n_stats, invn);
    else
        gemm_bt_k<false><<<g, b, 0, st>>>(a.A0, a.A1, a.A2, a.A3, a.nseg, a.segK, a.xmask,
            a.xstats, a.xg, a.xbb, a.Kx, a.Wt, a.bias, a.addb,
            a.o0, a.o1, a.o2, a.o3, a.ldo, a.n_store, a.ostats, a.Kostat, a.n_stats, invn);
}

extern "C" void kernel_launch(void* const* d_in, const int* in_sizes, int n_in,
                              void* d_out, int out_size, void* d_ws, size_t ws_size,
                              hipStream_t stream)
{
    const float* x       = (const float*)d_in[0];
    const int*   ei      = (const int*)d_in[1];
    const float* ew      = (const float*)d_in[2];
    const float* W_emb   = (const float*)d_in[3];
    const float* b_emb   = (const float*)d_in[4];
    const float* conv0_W = (const float*)d_in[5];
    const float* conv0_b = (const float*)d_in[6];
    const float* norm_g  = (const float*)d_in[7];
    const float* norm_b  = (const float*)d_in[8];
    const float* conv_W  = (const float*)d_in[9];
    const float* conv_b  = (const float*)d_in[10];
    const float* mlp_W1  = (const float*)d_in[11];
    const float* mlp_b1  = (const float*)d_in[12];
    const float* mlp_g   = (const float*)d_in[13];
    const float* mlp_bb  = (const float*)d_in[14];
    const float* mlp_W2  = (const float*)d_in[15];
    const float* mlp_b2  = (const float*)d_in[16];
    const float* W_out   = (const float*)d_in[17];
    const float* b_out   = (const float*)d_in[18];

    const int N = in_sizes[0] / 128;          // 50000
    const int E = in_sizes[2];                // 800000
    const int* srcI = ei;
    const int* dstI = ei + E;
    const int N_pad = ((N + 127) / 128) * 128;
    const int GY = N_pad / 128;

    const size_t NHp = (size_t)N_pad * HDIM;
    bf16* xb = (bf16*)d_ws;                      // N_pad x 128
    bf16* hb = xb + (size_t)N_pad * 128;
    bf16* cb = hb + NHp;
    bf16* p1 = cb + NHp;
    bf16* p2 = p1 + NHp;
    bf16* e1 = p2 + NHp;
    bf16* e2 = e1 + NHp;
    bf16* wa = e2 + NHp;                         // weight arena
    bf16* Wt_emb   = wa;
    bf16* Wt_conv0 = wa + 32768;
    bf16* Wt_conv  = wa + 229376;
    bf16* Wt_mlp1  = wa + 819200;
    bf16* Wt_mlp2  = wa + 1605632;
    bf16* Wt_out   = wa + 2392064;
    float* sh     = (float*)(wa + 2424832);      // 4 slots x 512
    float* sm     = sh + 2048;                   // 3 slots x 2048
    int*   rowptr = (int*)(sm + 6144);
    int*   wp     = rowptr + (N + 1);
    int*   col    = wp + N;
    float* wgt    = (float*)(col + E);

    const float invn = 1.0f / (float)N;
    dim3 pg((N + 3) / 4), pb(256);

    // ---- CSR build ----
    hipMemsetAsync(wp, 0, (size_t)N * 4, stream);
    deg_k<<<dim3((E + 255) / 256), dim3(256), 0, stream>>>(dstI, wp, E);
    scan_k<<<dim3(1), dim3(1024), 0, stream>>>(wp, rowptr, N);
    reorder_k<<<dim3((E + 255) / 256), dim3(256), 0, stream>>>(srcI, dstI, ew, wp, col, wgt, E);

    // ---- zero all stats slots ----
    hipMemsetAsync(sh, 0, 8192 * 4, stream);

    // ---- convert inputs/weights ----
    cvt_bf_k<<<dim3((N * 32 + 255) / 256), dim3(256), 0, stream>>>(x, xb, (long)N * 32);
    transpose_cvt_k<<<dim3(8, 4, 1), dim3(256), 0, stream>>>(W_emb, Wt_emb, 128, 256, 1);
    transpose_cvt_k<<<dim3(8, 8, 3), dim3(256), 0, stream>>>(conv0_W, Wt_conv0, 256, 256, 3);
    transpose_cvt_k<<<dim3(8, 8, 9), dim3(256), 0, stream>>>(conv_W, Wt_conv, 256, 256, 3);
    transpose_cvt_k<<<dim3(32, 8, 3), dim3(256), 0, stream>>>(mlp_W1, Wt_mlp1, 256, 1024, 1);
    transpose_cvt_k<<<dim3(8, 32, 3), dim3(256), 0, stream>>>(mlp_W2, Wt_mlp2, 1024, 256, 1);
    transpose_cvt_k<<<dim3(4, 8, 1), dim3(256), 0, stream>>>(W_out, Wt_out, 256, 128, 1);

    // ---- embed: cb = bf16(x @ W_emb + b_emb) ----
    {
        GemmArgs a{xb, xb, xb, xb, 1, 128, 0, nullptr, nullptr, nullptr, 0,
                   Wt_emb, b_emb, nullptr, cb, cb, cb, cb, HDIM, 256, N_pad,
                   nullptr, 0, 0};
        gemm(stream, a, GY, invn, true);
    }

    // ---- conv0: hb = [cb | A.cb | A^2.cb] @ Wt_conv0 + b; stats -> sh[0] ----
    spmm_pull_k<<<pg, pb, 0, stream>>>(cb, rowptr, col, wgt, p1, N, nullptr, nullptr, nullptr, invn);
    spmm_pull_k<<<pg, pb, 0, stream>>>(p1, rowptr, col, wgt, p2, N, nullptr, nullptr, nullptr, invn);
    {
        GemmArgs a{cb, p1, p2, p2, 3, 256, 0, nullptr, nullptr, nullptr, 0,
                   Wt_conv0, conv0_b, nullptr, hb, hb, hb, hb, HDIM, 256, N_pad,
                   sh, 256, N};
        gemm(stream, a, GY, invn, true);
    }

    for (int l = 0; l < 3; ++l) {
        float* shl = sh + l * 512;
        float* sml = sm + l * 2048;
        const float* ng = norm_g + l * 256;
        const float* nb = norm_b + l * 256;

        // p1 = A . leaky(bn(hb)); p2 = A . p1   (BN fused into hop-1 gather)
        spmm_pull_k<<<pg, pb, 0, stream>>>(hb, rowptr, col, wgt, p1, N, shl, ng, nb, invn);
        spmm_pull_k<<<pg, pb, 0, stream>>>(p1, rowptr, col, wgt, p2, N, nullptr, nullptr, nullptr, invn);

        // conv: cb = [bn(hb) | p1 | p2] @ Wl + b   (A0 transformed on stage)
        {
            GemmArgs a{hb, p1, p2, p2, 3, 256, 0x1, shl, ng, nb, 256,
                       Wt_conv + (size_t)l * 196608, conv_b + l * 256, nullptr,
                       cb, cb, cb, cb, HDIM, 256, N_pad, nullptr, 0, 0};
            gemm(stream, a, GY, invn, true);
        }

        // W1: {p1,p2,e1,e2} = cb @ W1 + b1 ; stats -> sm[l]
        {
            GemmArgs a{cb, cb, cb, cb, 1, 256, 0, nullptr, nullptr, nullptr, 0,
                       Wt_mlp1 + (size_t)l * 262144, mlp_b1 + (size_t)l * 1024, nullptr,
                       p1, p2, e1, e2, HDIM, 1024, N_pad, sml, 1024, N};
            gemm(stream, a, GY, invn, true);
        }

        // W2: hb += leaky(bn(hidden)) @ W2 + b2 ; stats -> sh[l+1]
        {
            GemmArgs a{p1, p2, e1, e2, 4, 256, 0xF, sml, mlp_g + (size_t)l * 1024,
                       mlp_bb + (size_t)l * 1024, 1024,
                       Wt_mlp2 + (size_t)l * 262144, mlp_b2 + l * 256, hb,
                       hb, hb, hb, hb, HDIM, 256, N_pad, sh + (l + 1) * 512, 256, N};
            gemm(stream, a, GY, invn, true);
        }
    }

    // ---- out = hb @ W_out + b_out (f32) ----
    {
        GemmArgs a{hb, hb, hb, hb, 1, 256, 0, nullptr, nullptr, nullptr, 0,
                   Wt_out, b_out, nullptr, d_out, d_out, d_out, d_out, 128, 128, N,
                   nullptr, 0, 0};
        gemm(stream, a, GY, invn, false);
    }
}